// Round 11
// baseline (464.253 us; speedup 1.0000x reference)
//
#include <hip/hip_runtime.h>
#include <hip/hip_fp16.h>

#define N_USERS 50000
#define N_ITEMS 75000
#define N_NODES 125000
#define N_PAD   125008               // padded to multiple of 16 for MFMA tiles
#define NNZ     1250000
#define EMB     64
#define N_LAYERS 3
#define BATCH   4096
#define CONCAT  256
#define NTILES  ((N_NODES + 15) / 16)         // 7813

#define BROWS   128                           // rows per bucket
#define NB      ((N_NODES + BROWS - 1) / BROWS)   // 977 buckets
#define CHUNK   4096                          // edges per partition block
#define NCHUNK  ((NNZ + CHUNK - 1) / CHUNK)   // 306
#define EPT     (CHUNK / 256)                 // 16 edges per thread
#define BCAP    1600                          // bucket capacity (mean 1280, +9 sigma)
#define ASTR    68                            // LDS agg tile row stride (fp32 words)

typedef _Float16 half8  __attribute__((ext_vector_type(8)));
typedef float    floatx4 __attribute__((ext_vector_type(4)));

// 'user' may be int64 (jax x64) or int32. Detect from data.
__device__ __forceinline__ bool user_is_i64(const void* uptr) {
    const int* u = (const int*)uptr;
    return (u[1] | u[3] | u[5] | u[7]) == 0;
}
__device__ __forceinline__ int load_user(const void* uptr, int b, bool is64) {
    return is64 ? (int)((const long long*)uptr)[b] : ((const int*)uptr)[b];
}
__device__ __forceinline__ int sample_node(const void* user, const int* pos,
                                           const int* neg, int which, int b,
                                           bool is64) {
    if (which == 0) return load_user(user, b, is64);
    return N_USERS + (which == 1 ? pos[b] : neg[b]);
}

// staged record (8B): [24..37] fp16(val) | [17..23] row&127 | [0..16] col
// final se word (4B): (fp16bits << 17) | col ;  word 0 => col 0, val +0.0
__device__ __forceinline__ float unpack_val(unsigned w) {
    unsigned short us = (unsigned short)(w >> 17);
    _Float16 h = __builtin_bit_cast(_Float16, us);
    return (float)h;
}

// ---------------------------------------------------------------------------
// init (+ fused gather0): f16 <- fp16(emb); out[:, 0:64] <- emb rows (fp32 exact)
// ---------------------------------------------------------------------------
__global__ void init_kernel(const float* __restrict__ emb,
                            _Float16* __restrict__ f16,
                            const void* __restrict__ user,
                            const int* __restrict__ pos,
                            const int* __restrict__ neg,
                            float* __restrict__ out) {
    int i = blockIdx.x * 256 + threadIdx.x;
    if (i < N_NODES * EMB) {
        f16[i] = (_Float16)emb[i];
    } else {
        int j = i - N_NODES * EMB;
        if (j < 3 * BATCH * EMB) {
            bool is64 = user_is_i64(user);
            int which = j / (BATCH * EMB);
            int rem   = j % (BATCH * EMB);
            int b = rem >> 6, d = rem & 63;
            int node = sample_node(user, pos, neg, which, b, is64);
            out[(which * BATCH + b) * CONCAT + d] = emb[node * EMB + d];
        }
    }
}

// ---------------------------------------------------------------------------
// P1: partition edges into fixed-capacity buckets, single LDS-atomic pass:
// per-edge pos captured from the histogram atomicAdd; store pass is atomic-free.
// ---------------------------------------------------------------------------
__global__ __launch_bounds__(256) void partition_kernel(
    const int* __restrict__ row, const int* __restrict__ col,
    const float* __restrict__ vals, int* __restrict__ bcnt,
    unsigned long long* __restrict__ sw8) {
    __shared__ int h[NB];
    __shared__ int base[NB];
    int t = threadIdx.x;
    int e0 = blockIdx.x * CHUNK;
    int e1 = e0 + CHUNK; if (e1 > NNZ) e1 = NNZ;
    for (int i = t; i < NB; i += 256) h[i] = 0;
    __syncthreads();

    unsigned long long rec[EPT];
    int bkt[EPT];
    int pos[EPT];
    int cnt = 0;
    for (int e = e0 + t; e < e1; e += 256) {
        int r = row[e];
        int b = r >> 7;
        _Float16 hv = (_Float16)vals[e];
        unsigned hb = (unsigned)__builtin_bit_cast(unsigned short, hv);
        rec[cnt] = ((unsigned long long)hb << 24)
                 | ((unsigned)(r & 127) << 17)
                 | (unsigned)col[e];
        bkt[cnt] = b;
        pos[cnt] = atomicAdd(&h[b], 1);
        ++cnt;
    }
    __syncthreads();
    for (int i = t; i < NB; i += 256) {
        int c = h[i];
        if (c) base[i] = atomicAdd(&bcnt[i], c);
    }
    __syncthreads();
    for (int k = 0; k < cnt; ++k) {
        int b = bkt[k];
        sw8[(size_t)b * BCAP + base[b] + pos[k]] = rec[k];
    }
}

// ---------------------------------------------------------------------------
// P2: scan bucket counts -> boff (final se layout); CSR sentinel.
// ---------------------------------------------------------------------------
__global__ __launch_bounds__(1024) void bucket_scan_kernel(
    const int* __restrict__ bcnt, int* __restrict__ boff, int* __restrict__ off) {
    __shared__ int s[1024];
    int t = threadIdx.x;
    int v = (t < NB) ? bcnt[t] : 0;
    s[t] = v;
    __syncthreads();
    for (int d = 1; d < 1024; d <<= 1) {
        int x = (t >= d) ? s[t - d] : 0;
        __syncthreads();
        s[t] += x;
        __syncthreads();
    }
    if (t < NB) boff[t] = s[t] - v;
    if (t == 0) { boff[NB] = NNZ; off[N_NODES] = NNZ; }
}

// ---------------------------------------------------------------------------
// P3: in-bucket counting sort (one block per bucket, all LDS) -> final CSR:
//   per-row off[] and row-sorted 4B se[], both written fully coalesced.
// ---------------------------------------------------------------------------
__global__ __launch_bounds__(256) void bucket_sort_kernel(
    const int* __restrict__ bcnt, const int* __restrict__ boff,
    const unsigned long long* __restrict__ sw8,
    unsigned* __restrict__ se, int* __restrict__ off) {
    __shared__ unsigned long long ew[BCAP];
    __shared__ unsigned eo[BCAP];
    __shared__ int rh[BROWS], rb[BROWS], rc[BROWS];
    __shared__ int s[256];

    int b = blockIdx.x, t = threadIdx.x;
    int n = bcnt[b];
    int s0 = boff[b];
    if (t < BROWS) rh[t] = 0;
    __syncthreads();
    const unsigned long long* src = sw8 + (size_t)b * BCAP;
    for (int i = t; i < n; i += 256) {
        unsigned long long rec = src[i];
        ew[i] = rec;
        atomicAdd(&rh[(int)((rec >> 17) & 127)], 1);
    }
    __syncthreads();
    s[t] = (t < BROWS) ? rh[t] : 0;
    __syncthreads();
    for (int d = 1; d < 256; d <<= 1) {
        int x = (t >= d) ? s[t - d] : 0;
        __syncthreads();
        s[t] += x;
        __syncthreads();
    }
    if (t < BROWS) {
        int excl = s[t] - rh[t];
        rb[t] = excl;
        rc[t] = 0;
        int r = b * BROWS + t;
        if (r < N_NODES) off[r] = s0 + excl;
    }
    __syncthreads();
    for (int i = t; i < n; i += 256) {
        unsigned long long rec = ew[i];
        int r = (int)((rec >> 17) & 127);
        int p = rb[r] + atomicAdd(&rc[r], 1);
        eo[p] = (unsigned)(((rec >> 24) << 17) | (rec & 0x1FFFFULL));
    }
    __syncthreads();
    for (int i = t; i < n; i += 256)
        se[s0 + i] = eo[i];
}

// ---------------------------------------------------------------------------
// fused layer: one wave per 16-node MFMA tile (grid-stride).
// Phase 1: gather agg for 16 nodes (lane=dim, 16-deep batch) -> LDS fp32 tile
//          (row stride 68 words: writes 2-way, b128 frag reads 2-way, 16B aligned).
// Phase 2: A-frags from LDS (fp32->fp16), fin frags from global, g=a*f in frag
//          space, 16 MFMAs, lrelu epilogue, fout16 frag-layout store.
// Same-wave LDS write->read: ordered, no barrier needed.
// ---------------------------------------------------------------------------
__global__ __launch_bounds__(256) void fused_layer_kernel(
    const int* __restrict__ off, const unsigned* __restrict__ se,
    const _Float16* __restrict__ fin, _Float16* __restrict__ fout,
    const float* __restrict__ W1, const float* __restrict__ b1,
    const float* __restrict__ W2, const float* __restrict__ b2, int layer) {

    __shared__ float alds[4][16 * ASTR];   // 4352 B per wave

    const int tid = threadIdx.x, wave = tid >> 6, lane = tid & 63;
    const int quad = lane >> 4, lm = lane & 15;

    // Preload W frags (fp16) + biases
    half8 bw1[4][2], bw2[4][2];
    float bias1[4], bias2[4];
    const float* W1l = W1 + layer * EMB * EMB;
    const float* W2l = W2 + layer * EMB * EMB;
    #pragma unroll
    for (int t = 0; t < 4; ++t) {
        int n = t * 16 + lm;
        bias1[t] = b1[layer * EMB + n];
        bias2[t] = b2[layer * EMB + n];
        #pragma unroll
        for (int kh = 0; kh < 2; ++kh) {
            const float* p1 = W1l + n * EMB + kh * 32 + quad * 8;
            const float* p2 = W2l + n * EMB + kh * 32 + quad * 8;
            floatx4 wa = *(const floatx4*)p1, wb = *(const floatx4*)(p1 + 4);
            floatx4 xa = *(const floatx4*)p2, xb = *(const floatx4*)(p2 + 4);
            half8 h1, h2;
            #pragma unroll
            for (int i = 0; i < 4; ++i) {
                h1[i] = (_Float16)wa[i]; h1[4 + i] = (_Float16)wb[i];
                h2[i] = (_Float16)xa[i]; h2[4 + i] = (_Float16)xb[i];
            }
            bw1[t][kh] = h1;
            bw2[t][kh] = h2;
        }
    }

    float* aw = alds[wave];

    for (int tile = blockIdx.x * 4 + wave; tile < NTILES; tile += gridDim.x * 4) {
        int nb = tile * 16;

        // ---- phase 1: gather agg rows (lane = dim) ----
        for (int i = 0; i < 16; ++i) {
            int n = nb + i;
            float acc = 0.f;
            if (n < N_NODES) {
                int j = off[n], end = off[n + 1];
                while (j < end) {
                    int c = end - j;
                    unsigned ev[16];
                    #pragma unroll
                    for (int t = 0; t < 16; ++t)
                        ev[t] = (t < c) ? se[j + t] : 0u;   // 0 => col 0, val +0.0
                    #pragma unroll
                    for (int t = 0; t < 16; ++t) {
                        int cc = (int)(ev[t] & 0x1FFFFu);
                        acc += unpack_val(ev[t]) * (float)fin[cc * EMB + lane];
                    }
                    j += 16;
                }
            }
            aw[i * ASTR + lane] = acc;
        }

        // ---- phase 2: MFMA dense ----
        const float* r = aw + lm * ASTR;
        floatx4 x0 = *(const floatx4*)(r + quad * 8);
        floatx4 x1 = *(const floatx4*)(r + quad * 8 + 4);
        floatx4 x2 = *(const floatx4*)(r + 32 + quad * 8);
        floatx4 x3 = *(const floatx4*)(r + 32 + quad * 8 + 4);
        half8 a0, a1;
        #pragma unroll
        for (int i = 0; i < 4; ++i) {
            a0[i] = (_Float16)x0[i]; a0[4 + i] = (_Float16)x1[i];
            a1[i] = (_Float16)x2[i]; a1[4 + i] = (_Float16)x3[i];
        }
        const half8* fp = (const half8*)(fin + (size_t)(nb + lm) * EMB + quad * 8);
        half8 f0 = fp[0], f1 = fp[4];
        half8 g0 = a0 * f0, g1 = a1 * f1;

        #pragma unroll
        for (int t = 0; t < 4; ++t) {
            floatx4 d1 = {0.f, 0.f, 0.f, 0.f}, d2 = {0.f, 0.f, 0.f, 0.f};
            d1 = __builtin_amdgcn_mfma_f32_16x16x32_f16(a0, bw1[t][0], d1, 0, 0, 0);
            d1 = __builtin_amdgcn_mfma_f32_16x16x32_f16(a1, bw1[t][1], d1, 0, 0, 0);
            d2 = __builtin_amdgcn_mfma_f32_16x16x32_f16(g0, bw2[t][0], d2, 0, 0, 0);
            d2 = __builtin_amdgcn_mfma_f32_16x16x32_f16(g1, bw2[t][1], d2, 0, 0, 0);
            int dim = t * 16 + lm;
            #pragma unroll
            for (int rr = 0; rr < 4; ++rr) {
                int node = nb + quad * 4 + rr;
                float p1v = d1[rr] + bias1[t];
                p1v = p1v > 0.f ? p1v : 0.2f * p1v;
                float p2v = d2[rr] + bias2[t];
                p2v = p2v > 0.f ? p2v : 0.2f * p2v;
                float nf = p1v + p2v;
                if (node < N_NODES)
                    fout[(size_t)node * EMB + dim] = (_Float16)nf;
            }
        }
    }
}

// ---------------------------------------------------------------------------
// gatherL: out[:, (l+1)*64 ...] <- l2_normalize(fp16 feat)[sampled nodes]
// ---------------------------------------------------------------------------
__global__ __launch_bounds__(256) void gatherL_kernel(
    const void* __restrict__ user, const int* __restrict__ pos,
    const int* __restrict__ neg, const _Float16* __restrict__ feat,
    float* __restrict__ out, int layer) {

    int w = blockIdx.x * 4 + (threadIdx.x >> 6);
    int lane = threadIdx.x & 63;
    if (w >= 3 * BATCH) return;
    bool is64 = user_is_i64(user);
    int which = w / BATCH, b = w % BATCH;
    int node = sample_node(user, pos, neg, which, b, is64);

    float f = (float)feat[(size_t)node * EMB + lane];
    float sq = f * f;
    #pragma unroll
    for (int off = 32; off; off >>= 1) sq += __shfl_xor(sq, off, 64);
    float norm = fmaxf(sqrtf(sq), 1e-12f);

    out[w * CONCAT + (layer + 1) * EMB + lane] = f / norm;
}

extern "C" void kernel_launch(void* const* d_in, const int* in_sizes, int n_in,
                              void* d_out, int out_size, void* d_ws, size_t ws_size,
                              hipStream_t stream) {
    const void* user = d_in[0];
    const int* pos  = (const int*)d_in[1];
    const int* neg  = (const int*)d_in[2];
    const int* row  = (const int*)d_in[3];
    const int* col  = (const int*)d_in[4];
    const float* vals = (const float*)d_in[5];
    const float* emb  = (const float*)d_in[6];
    const float* W1   = (const float*)d_in[7];
    const float* b1   = (const float*)d_in[8];
    const float* W2   = (const float*)d_in[9];
    const float* b2   = (const float*)d_in[10];

    // ws layout (all offsets 8B-aligned):
    _Float16* f16a   = (_Float16*)d_ws;                       // 16 MB
    _Float16* f16b   = f16a + (size_t)N_PAD * EMB;            // 16 MB
    int*      off    = (int*)(f16b + (size_t)N_PAD * EMB);    // 125008 ints
    int*      bcnt   = off + (N_NODES + 8);                   // 984 ints
    int*      boff   = bcnt + 984;                            // 984 ints
    unsigned long long* sw8 = (unsigned long long*)(boff + 984); // 977*1600*8 = 12.5 MB
    unsigned* se     = (unsigned*)(sw8 + (size_t)NB * BCAP);  // 5 MB final CSR

    float* out = (float*)d_out;

    // --- CSR build: fixed-cap bucket partition -> scan -> in-bucket sort ---
    hipMemsetAsync(bcnt, 0, (size_t)NB * sizeof(int), stream);
    partition_kernel<<<NCHUNK, 256, 0, stream>>>(row, col, vals, bcnt, sw8);
    bucket_scan_kernel<<<1, 1024, 0, stream>>>(bcnt, boff, off);
    bucket_sort_kernel<<<NB, 256, 0, stream>>>(bcnt, boff, sw8, se, off);

    // --- init + gather0 fused ---
    init_kernel<<<(N_NODES * EMB + 3 * BATCH * EMB + 255) / 256, 256, 0, stream>>>(
        emb, f16a, user, pos, neg, out);

    const _Float16* fin = f16a;
    _Float16* fout = f16b;
    for (int l = 0; l < N_LAYERS; ++l) {
        fused_layer_kernel<<<1024, 256, 0, stream>>>(off, se, fin, fout,
                                                     W1, b1, W2, b2, l);
        gatherL_kernel<<<(3 * BATCH + 3) / 4, 256, 0, stream>>>(
            user, pos, neg, fout, out, l);
        const _Float16* tmp = fout; fout = (_Float16*)fin; fin = (const _Float16*)tmp;
    }
}

// Round 12
// 348.857 us; speedup vs baseline: 1.3308x; 1.3308x over previous
//
#include <hip/hip_runtime.h>
#include <hip/hip_fp16.h>

#define N_USERS 50000
#define N_ITEMS 75000
#define N_NODES 125000
#define N_PAD   125008               // padded to multiple of 16 for MFMA tiles
#define NNZ     1250000
#define EMB     64
#define N_LAYERS 3
#define BATCH   4096
#define CONCAT  256
#define NTILES  ((N_NODES + 15) / 16)         // 7813

#define BROWS   128                           // rows per bucket
#define NB      ((N_NODES + BROWS - 1) / BROWS)   // 977 buckets
#define CHUNK   4096                          // edges per partition block
#define NCHUNK  ((NNZ + CHUNK - 1) / CHUNK)   // 306
#define EPT     (CHUNK / 256)                 // 16 edges per thread
#define BCAP    1600                          // bucket capacity (mean 1280, +9 sigma)

typedef _Float16 half8  __attribute__((ext_vector_type(8)));
typedef float    floatx4 __attribute__((ext_vector_type(4)));

// 'user' may be int64 (jax x64) or int32. Detect from data.
__device__ __forceinline__ bool user_is_i64(const void* uptr) {
    const int* u = (const int*)uptr;
    return (u[1] | u[3] | u[5] | u[7]) == 0;
}
__device__ __forceinline__ int load_user(const void* uptr, int b, bool is64) {
    return is64 ? (int)((const long long*)uptr)[b] : ((const int*)uptr)[b];
}
__device__ __forceinline__ int sample_node(const void* user, const int* pos,
                                           const int* neg, int which, int b,
                                           bool is64) {
    if (which == 0) return load_user(user, b, is64);
    return N_USERS + (which == 1 ? pos[b] : neg[b]);
}

// staged record (8B): [24..37] fp16(val) | [17..23] row&127 | [0..16] col
// final se word (4B): (fp16bits << 17) | col ;  word 0 => col 0, val +0.0
__device__ __forceinline__ float unpack_val(unsigned w) {
    unsigned short us = (unsigned short)(w >> 17);
    _Float16 h = __builtin_bit_cast(_Float16, us);
    return (float)h;
}

// ---------------------------------------------------------------------------
// init (+ fused gather0): f16 <- fp16(emb); out[:, 0:64] <- emb rows (fp32 exact)
// ---------------------------------------------------------------------------
__global__ void init_kernel(const float* __restrict__ emb,
                            _Float16* __restrict__ f16,
                            const void* __restrict__ user,
                            const int* __restrict__ pos,
                            const int* __restrict__ neg,
                            float* __restrict__ out) {
    int i = blockIdx.x * 256 + threadIdx.x;
    if (i < N_NODES * EMB) {
        f16[i] = (_Float16)emb[i];
    } else {
        int j = i - N_NODES * EMB;
        if (j < 3 * BATCH * EMB) {
            bool is64 = user_is_i64(user);
            int which = j / (BATCH * EMB);
            int rem   = j % (BATCH * EMB);
            int b = rem >> 6, d = rem & 63;
            int node = sample_node(user, pos, neg, which, b, is64);
            out[(which * BATCH + b) * CONCAT + d] = emb[node * EMB + d];
        }
    }
}

// ---------------------------------------------------------------------------
// P1: partition edges into fixed-capacity buckets, single LDS-atomic pass:
// per-edge pos captured from the histogram atomicAdd; store pass is atomic-free.
// ---------------------------------------------------------------------------
__global__ __launch_bounds__(256) void partition_kernel(
    const int* __restrict__ row, const int* __restrict__ col,
    const float* __restrict__ vals, int* __restrict__ bcnt,
    unsigned long long* __restrict__ sw8) {
    __shared__ int h[NB];
    __shared__ int base[NB];
    int t = threadIdx.x;
    int e0 = blockIdx.x * CHUNK;
    int e1 = e0 + CHUNK; if (e1 > NNZ) e1 = NNZ;
    for (int i = t; i < NB; i += 256) h[i] = 0;
    __syncthreads();

    unsigned long long rec[EPT];
    int bkt[EPT];
    int pos[EPT];
    int cnt = 0;
    for (int e = e0 + t; e < e1; e += 256) {
        int r = row[e];
        int b = r >> 7;
        _Float16 hv = (_Float16)vals[e];
        unsigned hb = (unsigned)__builtin_bit_cast(unsigned short, hv);
        rec[cnt] = ((unsigned long long)hb << 24)
                 | ((unsigned)(r & 127) << 17)
                 | (unsigned)col[e];
        bkt[cnt] = b;
        pos[cnt] = atomicAdd(&h[b], 1);
        ++cnt;
    }
    __syncthreads();
    for (int i = t; i < NB; i += 256) {
        int c = h[i];
        if (c) base[i] = atomicAdd(&bcnt[i], c);
    }
    __syncthreads();
    for (int k = 0; k < cnt; ++k) {
        int b = bkt[k];
        sw8[(size_t)b * BCAP + base[b] + pos[k]] = rec[k];
    }
}

// ---------------------------------------------------------------------------
// P2: scan bucket counts -> boff (final se layout); CSR sentinel.
// ---------------------------------------------------------------------------
__global__ __launch_bounds__(1024) void bucket_scan_kernel(
    const int* __restrict__ bcnt, int* __restrict__ boff, int* __restrict__ off) {
    __shared__ int s[1024];
    int t = threadIdx.x;
    int v = (t < NB) ? bcnt[t] : 0;
    s[t] = v;
    __syncthreads();
    for (int d = 1; d < 1024; d <<= 1) {
        int x = (t >= d) ? s[t - d] : 0;
        __syncthreads();
        s[t] += x;
        __syncthreads();
    }
    if (t < NB) boff[t] = s[t] - v;
    if (t == 0) { boff[NB] = NNZ; off[N_NODES] = NNZ; }
}

// ---------------------------------------------------------------------------
// P3: in-bucket counting sort (one block per bucket, all LDS) -> final CSR:
//   per-row off[] and row-sorted 4B se[], both written fully coalesced.
// ---------------------------------------------------------------------------
__global__ __launch_bounds__(256) void bucket_sort_kernel(
    const int* __restrict__ bcnt, const int* __restrict__ boff,
    const unsigned long long* __restrict__ sw8,
    unsigned* __restrict__ se, int* __restrict__ off) {
    __shared__ unsigned long long ew[BCAP];
    __shared__ unsigned eo[BCAP];
    __shared__ int rh[BROWS], rb[BROWS], rc[BROWS];
    __shared__ int s[256];

    int b = blockIdx.x, t = threadIdx.x;
    int n = bcnt[b];
    int s0 = boff[b];
    if (t < BROWS) rh[t] = 0;
    __syncthreads();
    const unsigned long long* src = sw8 + (size_t)b * BCAP;
    for (int i = t; i < n; i += 256) {
        unsigned long long rec = src[i];
        ew[i] = rec;
        atomicAdd(&rh[(int)((rec >> 17) & 127)], 1);
    }
    __syncthreads();
    s[t] = (t < BROWS) ? rh[t] : 0;
    __syncthreads();
    for (int d = 1; d < 256; d <<= 1) {
        int x = (t >= d) ? s[t - d] : 0;
        __syncthreads();
        s[t] += x;
        __syncthreads();
    }
    if (t < BROWS) {
        int excl = s[t] - rh[t];
        rb[t] = excl;
        rc[t] = 0;
        int r = b * BROWS + t;
        if (r < N_NODES) off[r] = s0 + excl;
    }
    __syncthreads();
    for (int i = t; i < n; i += 256) {
        unsigned long long rec = ew[i];
        int r = (int)((rec >> 17) & 127);
        int p = rb[r] + atomicAdd(&rc[r], 1);
        eo[p] = (unsigned)(((rec >> 24) << 17) | (rec & 0x1FFFFULL));
    }
    __syncthreads();
    for (int i = t; i < n; i += 256)
        se[s0 + i] = eo[i];
}

// ---------------------------------------------------------------------------
// SpMM gather: one wave per node (max TLP — the gather is latency-bound and
// needs wave count, not per-wave work; round-11's 16-node-per-wave fusion
// regressed for exactly this reason). 16-deep edge batch.
// ---------------------------------------------------------------------------
__global__ __launch_bounds__(256) void spmm_kernel(
    const int* __restrict__ off, const unsigned* __restrict__ se,
    const _Float16* __restrict__ fin, _Float16* __restrict__ agg16) {
    int w = blockIdx.x * 4 + (threadIdx.x >> 6);
    int lane = threadIdx.x & 63;
    if (w >= N_NODES) return;
    int j = off[w], end = off[w + 1];
    float acc = 0.f;
    while (j < end) {
        int cnt = end - j;
        unsigned ev[16];
        #pragma unroll
        for (int t = 0; t < 16; ++t)
            ev[t] = (t < cnt) ? se[j + t] : 0u;   // 0 => col 0, val +0.0
        #pragma unroll
        for (int t = 0; t < 16; ++t) {
            int c = (int)(ev[t] & 0x1FFFFu);
            acc += unpack_val(ev[t]) * (float)fin[c * EMB + lane];
        }
        j += 16;
    }
    agg16[w * EMB + lane] = (_Float16)acc;
}

// ---------------------------------------------------------------------------
// dense via MFMA f16: one wave = 16 nodes x 64 dims (4 n-tiles of 16).
//   p1 = lrelu(agg @ W1^T + b1); p2 = lrelu((agg*fin) @ W2^T + b2)
//   fout16 <- fp16(p1+p2)
// ---------------------------------------------------------------------------
__global__ __launch_bounds__(256) void dense_kernel(
    const _Float16* __restrict__ agg16, const _Float16* __restrict__ fin,
    _Float16* __restrict__ fout,
    const float* __restrict__ W1, const float* __restrict__ b1,
    const float* __restrict__ W2, const float* __restrict__ b2, int layer) {

    const int tid = threadIdx.x, wave = tid >> 6, lane = tid & 63;
    const int quad = lane >> 4, lm = lane & 15;

    half8 bw1[4][2], bw2[4][2];
    float bias1[4], bias2[4];
    const float* W1l = W1 + layer * EMB * EMB;
    const float* W2l = W2 + layer * EMB * EMB;
    #pragma unroll
    for (int t = 0; t < 4; ++t) {
        int n = t * 16 + lm;
        bias1[t] = b1[layer * EMB + n];
        bias2[t] = b2[layer * EMB + n];
        #pragma unroll
        for (int kh = 0; kh < 2; ++kh) {
            const float* p1 = W1l + n * EMB + kh * 32 + quad * 8;
            const float* p2 = W2l + n * EMB + kh * 32 + quad * 8;
            floatx4 wa = *(const floatx4*)p1, wb = *(const floatx4*)(p1 + 4);
            floatx4 xa = *(const floatx4*)p2, xb = *(const floatx4*)(p2 + 4);
            half8 h1, h2;
            #pragma unroll
            for (int i = 0; i < 4; ++i) {
                h1[i] = (_Float16)wa[i]; h1[4 + i] = (_Float16)wb[i];
                h2[i] = (_Float16)xa[i]; h2[4 + i] = (_Float16)xb[i];
            }
            bw1[t][kh] = h1;
            bw2[t][kh] = h2;
        }
    }

    for (int tile = blockIdx.x * 4 + wave; tile < NTILES; tile += gridDim.x * 4) {
        int nb = tile * 16;
        const half8* ap = (const half8*)(agg16 + (size_t)(nb + lm) * EMB + quad * 8);
        const half8* fp = (const half8*)(fin   + (size_t)(nb + lm) * EMB + quad * 8);
        half8 a0 = ap[0], a1 = ap[4];   // k in [0,32) and [32,64)
        half8 f0 = fp[0], f1 = fp[4];
        half8 g0 = a0 * f0, g1 = a1 * f1;

        #pragma unroll
        for (int t = 0; t < 4; ++t) {
            floatx4 d1 = {0.f, 0.f, 0.f, 0.f}, d2 = {0.f, 0.f, 0.f, 0.f};
            d1 = __builtin_amdgcn_mfma_f32_16x16x32_f16(a0, bw1[t][0], d1, 0, 0, 0);
            d1 = __builtin_amdgcn_mfma_f32_16x16x32_f16(a1, bw1[t][1], d1, 0, 0, 0);
            d2 = __builtin_amdgcn_mfma_f32_16x16x32_f16(g0, bw2[t][0], d2, 0, 0, 0);
            d2 = __builtin_amdgcn_mfma_f32_16x16x32_f16(g1, bw2[t][1], d2, 0, 0, 0);
            int dim = t * 16 + lm;
            #pragma unroll
            for (int r = 0; r < 4; ++r) {
                int node = nb + quad * 4 + r;
                float p1v = d1[r] + bias1[t];
                p1v = p1v > 0.f ? p1v : 0.2f * p1v;
                float p2v = d2[r] + bias2[t];
                p2v = p2v > 0.f ? p2v : 0.2f * p2v;
                float nf = p1v + p2v;
                if (node < N_NODES)
                    fout[(size_t)node * EMB + dim] = (_Float16)nf;
            }
        }
    }
}

// ---------------------------------------------------------------------------
// gatherL: out[:, (l+1)*64 ...] <- l2_normalize(fp16 feat)[sampled nodes]
// ---------------------------------------------------------------------------
__global__ __launch_bounds__(256) void gatherL_kernel(
    const void* __restrict__ user, const int* __restrict__ pos,
    const int* __restrict__ neg, const _Float16* __restrict__ feat,
    float* __restrict__ out, int layer) {

    int w = blockIdx.x * 4 + (threadIdx.x >> 6);
    int lane = threadIdx.x & 63;
    if (w >= 3 * BATCH) return;
    bool is64 = user_is_i64(user);
    int which = w / BATCH, b = w % BATCH;
    int node = sample_node(user, pos, neg, which, b, is64);

    float f = (float)feat[(size_t)node * EMB + lane];
    float sq = f * f;
    #pragma unroll
    for (int off = 32; off; off >>= 1) sq += __shfl_xor(sq, off, 64);
    float norm = fmaxf(sqrtf(sq), 1e-12f);

    out[w * CONCAT + (layer + 1) * EMB + lane] = f / norm;
}

extern "C" void kernel_launch(void* const* d_in, const int* in_sizes, int n_in,
                              void* d_out, int out_size, void* d_ws, size_t ws_size,
                              hipStream_t stream) {
    const void* user = d_in[0];
    const int* pos  = (const int*)d_in[1];
    const int* neg  = (const int*)d_in[2];
    const int* row  = (const int*)d_in[3];
    const int* col  = (const int*)d_in[4];
    const float* vals = (const float*)d_in[5];
    const float* emb  = (const float*)d_in[6];
    const float* W1   = (const float*)d_in[7];
    const float* b1   = (const float*)d_in[8];
    const float* W2   = (const float*)d_in[9];
    const float* b2   = (const float*)d_in[10];

    // ws layout (all offsets 8B-aligned):
    _Float16* f16a   = (_Float16*)d_ws;                       // 16 MB
    _Float16* f16b   = f16a + (size_t)N_PAD * EMB;            // 16 MB
    _Float16* agg16  = f16b + (size_t)N_PAD * EMB;            // 16 MB
    int*      off    = (int*)(agg16 + (size_t)N_PAD * EMB);   // 125008 ints
    int*      bcnt   = off + (N_NODES + 8);                   // 984 ints
    int*      boff   = bcnt + 984;                            // 984 ints
    unsigned long long* sw8 = (unsigned long long*)(boff + 984); // 977*1600*8 = 12.5 MB
    unsigned* se     = (unsigned*)(sw8 + (size_t)NB * BCAP);  // 5 MB final CSR

    float* out = (float*)d_out;

    // --- CSR build: fixed-cap bucket partition -> scan -> in-bucket sort ---
    hipMemsetAsync(bcnt, 0, (size_t)NB * sizeof(int), stream);
    partition_kernel<<<NCHUNK, 256, 0, stream>>>(row, col, vals, bcnt, sw8);
    bucket_scan_kernel<<<1, 1024, 0, stream>>>(bcnt, boff, off);
    bucket_sort_kernel<<<NB, 256, 0, stream>>>(bcnt, boff, sw8, se, off);

    // --- init + gather0 fused ---
    init_kernel<<<(N_NODES * EMB + 3 * BATCH * EMB + 255) / 256, 256, 0, stream>>>(
        emb, f16a, user, pos, neg, out);

    const _Float16* fin = f16a;
    _Float16* fout = f16b;
    for (int l = 0; l < N_LAYERS; ++l) {
        spmm_kernel<<<(N_NODES + 3) / 4, 256, 0, stream>>>(off, se, fin, agg16);
        dense_kernel<<<1024, 256, 0, stream>>>(agg16, fin, fout, W1, b1, W2, b2, l);
        gatherL_kernel<<<(3 * BATCH + 3) / 4, 256, 0, stream>>>(
            user, pos, neg, fout, out, l);
        const _Float16* tmp = fout; fout = (_Float16*)fin; fin = (const _Float16*)tmp;
    }
}